// Round 6
// baseline (60926.056 us; speedup 1.0000x reference)
//
#include <hip/hip_runtime.h>
#include <math.h>

#define BB 512   // batch
#define TT 256   // time steps
#define EE 128   // hidden
#define GG 512   // 4*E gates
#define XROW 257 // T+1

// sigmoid and tanh via one shared exp path: tanh(x) = 2*sigmoid(2x) - 1
__device__ __forceinline__ float sig_(float v) {
    return 1.0f / (1.0f + __expf(-v));
}
__device__ __forceinline__ float tanh2_(float v) {
    return fmaf(2.0f, sig_(2.0f * v), -1.0f);
}

// Thread (rg=t&63, cg=t>>6) owns gate rows 8rg..8rg+7, cols 32cg..32cg+31:
// 256 weights in 256 NAMED SCALAR floats, asm-pinned to VGPRs.
#define DECL_ROW(R) float w##R##_0,w##R##_1,w##R##_2,w##R##_3,w##R##_4,w##R##_5,w##R##_6,w##R##_7, \
  w##R##_8,w##R##_9,w##R##_10,w##R##_11,w##R##_12,w##R##_13,w##R##_14,w##R##_15, \
  w##R##_16,w##R##_17,w##R##_18,w##R##_19,w##R##_20,w##R##_21,w##R##_22,w##R##_23, \
  w##R##_24,w##R##_25,w##R##_26,w##R##_27,w##R##_28,w##R##_29,w##R##_30,w##R##_31
#define DECLW DECL_ROW(0); DECL_ROW(1); DECL_ROW(2); DECL_ROW(3); \
              DECL_ROW(4); DECL_ROW(5); DECL_ROW(6); DECL_ROW(7)

#define LOAD_ROW(R, P) do { const float4* _q = (const float4*)(P); \
  float4 _a=_q[0],_b=_q[1],_c=_q[2],_d=_q[3],_e=_q[4],_f=_q[5],_g=_q[6],_h=_q[7]; \
  w##R##_0 =_a.x; w##R##_1 =_a.y; w##R##_2 =_a.z; w##R##_3 =_a.w; \
  w##R##_4 =_b.x; w##R##_5 =_b.y; w##R##_6 =_b.z; w##R##_7 =_b.w; \
  w##R##_8 =_c.x; w##R##_9 =_c.y; w##R##_10=_c.z; w##R##_11=_c.w; \
  w##R##_12=_d.x; w##R##_13=_d.y; w##R##_14=_d.z; w##R##_15=_d.w; \
  w##R##_16=_e.x; w##R##_17=_e.y; w##R##_18=_e.z; w##R##_19=_e.w; \
  w##R##_20=_f.x; w##R##_21=_f.y; w##R##_22=_f.z; w##R##_23=_f.w; \
  w##R##_24=_g.x; w##R##_25=_g.y; w##R##_26=_g.z; w##R##_27=_g.w; \
  w##R##_28=_h.x; w##R##_29=_h.y; w##R##_30=_h.z; w##R##_31=_h.w; } while(0)
// base P points at row (8rg), stride EE floats per row
#define LOADW(P) do { const float* _pp = (P); \
  LOAD_ROW(0,_pp); LOAD_ROW(1,_pp+EE); LOAD_ROW(2,_pp+2*EE); LOAD_ROW(3,_pp+3*EE); \
  LOAD_ROW(4,_pp+4*EE); LOAD_ROW(5,_pp+5*EE); LOAD_ROW(6,_pp+6*EE); LOAD_ROW(7,_pp+7*EE); } while(0)

#define KEEP_ROW(R) do { asm volatile("" : \
  "+v"(w##R##_0),"+v"(w##R##_1),"+v"(w##R##_2),"+v"(w##R##_3), \
  "+v"(w##R##_4),"+v"(w##R##_5),"+v"(w##R##_6),"+v"(w##R##_7), \
  "+v"(w##R##_8),"+v"(w##R##_9),"+v"(w##R##_10),"+v"(w##R##_11), \
  "+v"(w##R##_12),"+v"(w##R##_13),"+v"(w##R##_14),"+v"(w##R##_15)); \
  asm volatile("" : \
  "+v"(w##R##_16),"+v"(w##R##_17),"+v"(w##R##_18),"+v"(w##R##_19), \
  "+v"(w##R##_20),"+v"(w##R##_21),"+v"(w##R##_22),"+v"(w##R##_23), \
  "+v"(w##R##_24),"+v"(w##R##_25),"+v"(w##R##_26),"+v"(w##R##_27), \
  "+v"(w##R##_28),"+v"(w##R##_29),"+v"(w##R##_30),"+v"(w##R##_31)); } while(0)
#define KEEPW do { KEEP_ROW(0); KEEP_ROW(1); KEEP_ROW(2); KEEP_ROW(3); \
                   KEEP_ROW(4); KEEP_ROW(5); KEEP_ROW(6); KEEP_ROW(7); } while(0)

#define FMA_ROW(R, A) do { \
  A=fmaf(w##R##_0 ,hx0.x,A); A=fmaf(w##R##_1 ,hx0.y,A); A=fmaf(w##R##_2 ,hx0.z,A); A=fmaf(w##R##_3 ,hx0.w,A); \
  A=fmaf(w##R##_4 ,hx1.x,A); A=fmaf(w##R##_5 ,hx1.y,A); A=fmaf(w##R##_6 ,hx1.z,A); A=fmaf(w##R##_7 ,hx1.w,A); \
  A=fmaf(w##R##_8 ,hx2.x,A); A=fmaf(w##R##_9 ,hx2.y,A); A=fmaf(w##R##_10,hx2.z,A); A=fmaf(w##R##_11,hx2.w,A); \
  A=fmaf(w##R##_12,hx3.x,A); A=fmaf(w##R##_13,hx3.y,A); A=fmaf(w##R##_14,hx3.z,A); A=fmaf(w##R##_15,hx3.w,A); \
  A=fmaf(w##R##_16,hx4.x,A); A=fmaf(w##R##_17,hx4.y,A); A=fmaf(w##R##_18,hx4.z,A); A=fmaf(w##R##_19,hx4.w,A); \
  A=fmaf(w##R##_20,hx5.x,A); A=fmaf(w##R##_21,hx5.y,A); A=fmaf(w##R##_22,hx5.z,A); A=fmaf(w##R##_23,hx5.w,A); \
  A=fmaf(w##R##_24,hx6.x,A); A=fmaf(w##R##_25,hx6.y,A); A=fmaf(w##R##_26,hx6.z,A); A=fmaf(w##R##_27,hx6.w,A); \
  A=fmaf(w##R##_28,hx7.x,A); A=fmaf(w##R##_29,hx7.y,A); A=fmaf(w##R##_30,hx7.z,A); A=fmaf(w##R##_31,hx7.w,A); } while(0)

// dot phase: 8 broadcast ds_read_b128 (wave-uniform cg), 256 FMA, 8 swizzled
// conflict-free b32 partial writes (part[cg][rr][ (rg+8rr)&63 ]).
#define DOT_PHASE() do { \
  const float4* _h4 = (const float4*)(h_lds + 32*cg); \
  float4 hx0=_h4[0],hx1=_h4[1],hx2=_h4[2],hx3=_h4[3], \
         hx4=_h4[4],hx5=_h4[5],hx6=_h4[6],hx7=_h4[7]; \
  float a0=0.f,a1=0.f,a2=0.f,a3=0.f,a4=0.f,a5=0.f,a6=0.f,a7=0.f; \
  FMA_ROW(0,a0); FMA_ROW(1,a1); FMA_ROW(2,a2); FMA_ROW(3,a3); \
  FMA_ROW(4,a4); FMA_ROW(5,a5); FMA_ROW(6,a6); FMA_ROW(7,a7); \
  part[pw0]=a0; part[pw1]=a1; part[pw2]=a2; part[pw3]=a3; \
  part[pw4]=a4; part[pw5]=a5; part[pw6]=a6; part[pw7]=a7; \
} while(0)

__global__ void fused_kernel(const float* __restrict__ x,
                  const float* __restrict__ enc_wih,
                  const float* __restrict__ enc_whh,
                  const float* __restrict__ enc_bias,
                  const float* __restrict__ dec_wih,
                  const float* __restrict__ dec_whh,
                  const float* __restrict__ dec_bias,
                  const float* __restrict__ lin_w,
                  const float* __restrict__ lin_b,
                  float* __restrict__ out)
{
    const int t  = threadIdx.x;   // 256 threads
    const int rg = t & 63;
    const int cg = t >> 6;        // == wave id -> h reads are pure broadcast
    const int b  = blockIdx.x;

    __shared__ __align__(16) float h_lds[EE];
    __shared__ __align__(16) float part[4 * GG];   // [cg][rr][swz(rg)] 8 KB
    __shared__ __align__(16) float out_lds[TT];
    __shared__ float xbuf[2];
    __shared__ float osum[2];

    const int id = (int)x[b * XROW + TT];

    // part write indices (swizzled, conflict-free; precomputed once)
    const int pbase = cg * 512;
    const int pw0 = pbase + 0*64 + ((rg + 0 ) & 63);
    const int pw1 = pbase + 1*64 + ((rg + 8 ) & 63);
    const int pw2 = pbase + 2*64 + ((rg + 16) & 63);
    const int pw3 = pbase + 3*64 + ((rg + 24) & 63);
    const int pw4 = pbase + 4*64 + ((rg + 32) & 63);
    const int pw5 = pbase + 5*64 + ((rg + 40) & 63);
    const int pw6 = pbase + 6*64 + ((rg + 48) & 63);
    const int pw7 = pbase + 7*64 + ((rg + 56) & 63);
    // psum read offsets for element q=t (<128): row r=q+128m ->
    // off_m = (q&7)*64 + ((q>>3) + 16m + 8*(q&7)) & 63   (2-way max = free)
    const int q = t;
    const int b0_ = (q&7)*64 + (((q>>3) + 0  + 8*(q&7)) & 63);
    const int b1_ = (q&7)*64 + (((q>>3) + 16 + 8*(q&7)) & 63);
    const int b2_ = (q&7)*64 + (((q>>3) + 32 + 8*(q&7)) & 63);
    const int b3_ = (q&7)*64 + (((q>>3) + 48 + 8*(q&7)) & 63);

    DECLW;
    float c_reg = 0.0f;
    float wih0=0.f,wih1=0.f,wih2=0.f,wih3=0.f, bb0=0.f,bb1=0.f,bb2=0.f,bb3=0.f;
    const float lb_v = lin_b[id];
    float wl = 0.0f;
    if (t < EE) wl = lin_w[id * EE + t];

    // ---------------- encoder ----------------
    LOADW(enc_whh + (8 * rg) * EE + 32 * cg);
    if (t < EE) {
        wih0 = enc_wih[t];        bb0 = enc_bias[t];
        wih1 = enc_wih[EE + t];   bb1 = enc_bias[EE + t];
        wih2 = enc_wih[2*EE + t]; bb2 = enc_bias[2*EE + t];
        wih3 = enc_wih[3*EE + t]; bb3 = enc_bias[3*EE + t];
        h_lds[t] = 0.0f;
    }
    if (t == 0) xbuf[0] = x[b * XROW + 0];
    __syncthreads();

    for (int s = 0; s < TT; ++s) {
        KEEPW;
        DOT_PHASE();
        if (t == 193 && s + 1 < TT) xbuf[(s + 1) & 1] = x[b * XROW + s + 1];
        __syncthreads();
        if (t < EE) {
            float u = xbuf[s & 1];
            float g0 = part[b0_] + part[512+b0_] + part[1024+b0_] + part[1536+b0_];
            float g1 = part[b1_] + part[512+b1_] + part[1024+b1_] + part[1536+b1_];
            float g2 = part[b2_] + part[512+b2_] + part[1024+b2_] + part[1536+b2_];
            float g3 = part[b3_] + part[512+b3_] + part[1024+b3_] + part[1536+b3_];
            float i_ = sig_(g0 + fmaf(u, wih0, bb0));
            float f_ = sig_(g1 + fmaf(u, wih1, bb1));
            float gg = tanh2_(g2 + fmaf(u, wih2, bb2));
            float o_ = sig_(g3 + fmaf(u, wih3, bb3));
            c_reg = fmaf(f_, c_reg, i_ * gg);
            h_lds[t] = o_ * tanh2_(c_reg);
        }
        __syncthreads();
    }

    // ---------------- u0 + decoder weight swap ----------------
    LOADW(dec_whh + id * GG * EE + (8 * rg) * EE + 32 * cg);
    if (t < EE) {
        float p = h_lds[t] * wl;
        #pragma unroll
        for (int off = 32; off >= 1; off >>= 1) p += __shfl_xor(p, off);
        if ((t & 63) == 0) osum[t >> 6] = p;
        wih0 = dec_wih[id*GG + t];        bb0 = dec_bias[id*GG + t];
        wih1 = dec_wih[id*GG + EE + t];   bb1 = dec_bias[id*GG + EE + t];
        wih2 = dec_wih[id*GG + 2*EE + t]; bb2 = dec_bias[id*GG + 2*EE + t];
        wih3 = dec_wih[id*GG + 3*EE + t]; bb3 = dec_bias[id*GG + 3*EE + t];
    }
    __syncthreads();
    if (t == 0) xbuf[0] = osum[0] + osum[1] + lb_v;   // u0
    __syncthreads();

    // ---------------- decoder ----------------
    for (int s = 0; s < TT; ++s) {
        KEEPW;
        DOT_PHASE();
        // u_{s+1} = rev[s] = x[b][255-s]
        if (t == 193 && s + 1 < TT) xbuf[(s + 1) & 1] = x[b * XROW + (TT - 1 - s)];
        // previous step's output (osum stable during dot phase)
        if (t == 192 && s > 0) out_lds[TT - s] = osum[0] + osum[1] + lb_v;
        __syncthreads();
        if (t < EE) {
            float u = xbuf[s & 1];
            float g0 = part[b0_] + part[512+b0_] + part[1024+b0_] + part[1536+b0_];
            float g1 = part[b1_] + part[512+b1_] + part[1024+b1_] + part[1536+b1_];
            float g2 = part[b2_] + part[512+b2_] + part[1024+b2_] + part[1536+b2_];
            float g3 = part[b3_] + part[512+b3_] + part[1024+b3_] + part[1536+b3_];
            float i_ = sig_(g0 + fmaf(u, wih0, bb0));
            float f_ = sig_(g1 + fmaf(u, wih1, bb1));
            float gg = tanh2_(g2 + fmaf(u, wih2, bb2));
            float o_ = sig_(g3 + fmaf(u, wih3, bb3));
            c_reg = fmaf(f_, c_reg, i_ * gg);
            float h_new = o_ * tanh2_(c_reg);
            h_lds[t] = h_new;
            float p = h_new * wl;
            #pragma unroll
            for (int off = 32; off >= 1; off >>= 1) p += __shfl_xor(p, off);
            if ((t & 63) == 0) osum[t >> 6] = p;
        }
        __syncthreads();
    }
    if (t == 192) out_lds[0] = osum[0] + osum[1] + lb_v;  // step 255 -> pos 0
    __syncthreads();

    if (t < 64) *(float4*)(out + b * TT + 4 * t) = ((const float4*)out_lds)[t];
}

extern "C" void kernel_launch(void* const* d_in, const int* in_sizes, int n_in,
                              void* d_out, int out_size, void* d_ws, size_t ws_size,
                              hipStream_t stream) {
    const float* x       = (const float*)d_in[0];
    const float* enc_wih = (const float*)d_in[1];
    const float* enc_whh = (const float*)d_in[2];
    const float* enc_b   = (const float*)d_in[3];
    const float* dec_wih = (const float*)d_in[4];
    const float* dec_whh = (const float*)d_in[5];
    const float* dec_b   = (const float*)d_in[6];
    const float* lin_w   = (const float*)d_in[7];
    const float* lin_b   = (const float*)d_in[8];
    float* out = (float*)d_out;

    hipLaunchKernelGGL(fused_kernel, dim3(BB), dim3(256), 0, stream,
                       x, enc_wih, enc_whh, enc_b,
                       dec_wih, dec_whh, dec_b, lin_w, lin_b, out);
}

// Round 7
// 1126.673 us; speedup vs baseline: 54.0761x; 54.0761x over previous
//
#include <hip/hip_runtime.h>
#include <math.h>

#define BB 512   // batch
#define TT 256   // time steps
#define EE 128   // hidden
#define GG 512   // 4*E gates
#define XROW 257 // T+1

// sigmoid and tanh via one shared exp path: tanh(x) = 2*sigmoid(2x) - 1
__device__ __forceinline__ float sig_(float v) {
    return 1.0f / (1.0f + __expf(-v));
}
__device__ __forceinline__ float tanh2_(float v) {
    return fmaf(2.0f, sig_(2.0f * v), -1.0f);
}

// Thread (rg = t&127, cg = t>>7) owns rows 4rg..4rg+3 x cols 16cg..16cg+15.
// 64 weights in 64 NAMED SCALAR floats, asm-pinned (scalar "+v" is the only
// compile-safe tied constraint -- float4 operands fail, see round 4).
#define DECL_ROW(R) float w##R##_0,w##R##_1,w##R##_2,w##R##_3,w##R##_4,w##R##_5, \
  w##R##_6,w##R##_7,w##R##_8,w##R##_9,w##R##_10,w##R##_11,w##R##_12,w##R##_13, \
  w##R##_14,w##R##_15
#define DECLW DECL_ROW(0); DECL_ROW(1); DECL_ROW(2); DECL_ROW(3)

#define LOAD_ROW(R, P) do { const float4* _q = (const float4*)(P); \
  float4 _a=_q[0], _b=_q[1], _c=_q[2], _d=_q[3]; \
  w##R##_0=_a.x;  w##R##_1=_a.y;  w##R##_2=_a.z;  w##R##_3=_a.w; \
  w##R##_4=_b.x;  w##R##_5=_b.y;  w##R##_6=_b.z;  w##R##_7=_b.w; \
  w##R##_8=_c.x;  w##R##_9=_c.y;  w##R##_10=_c.z; w##R##_11=_c.w; \
  w##R##_12=_d.x; w##R##_13=_d.y; w##R##_14=_d.z; w##R##_15=_d.w; } while(0)
#define LOADW(P) do { const float* _pp = (P); \
  LOAD_ROW(0, _pp); LOAD_ROW(1, _pp + EE); \
  LOAD_ROW(2, _pp + 2*EE); LOAD_ROW(3, _pp + 3*EE); } while(0)

#define KEEP_ROW(R) asm volatile("" : \
  "+v"(w##R##_0),"+v"(w##R##_1),"+v"(w##R##_2),"+v"(w##R##_3), \
  "+v"(w##R##_4),"+v"(w##R##_5),"+v"(w##R##_6),"+v"(w##R##_7), \
  "+v"(w##R##_8),"+v"(w##R##_9),"+v"(w##R##_10),"+v"(w##R##_11), \
  "+v"(w##R##_12),"+v"(w##R##_13),"+v"(w##R##_14),"+v"(w##R##_15))
#define KEEPW do { KEEP_ROW(0); KEEP_ROW(1); KEEP_ROW(2); KEEP_ROW(3); } while(0)

#define FMA_ROW(R, A) do { \
  A=fmaf(w##R##_0 , x0.x, A); A=fmaf(w##R##_1 , x0.y, A); \
  A=fmaf(w##R##_2 , x0.z, A); A=fmaf(w##R##_3 , x0.w, A); \
  A=fmaf(w##R##_4 , x1.x, A); A=fmaf(w##R##_5 , x1.y, A); \
  A=fmaf(w##R##_6 , x1.z, A); A=fmaf(w##R##_7 , x1.w, A); \
  A=fmaf(w##R##_8 , x2.x, A); A=fmaf(w##R##_9 , x2.y, A); \
  A=fmaf(w##R##_10, x2.z, A); A=fmaf(w##R##_11, x2.w, A); \
  A=fmaf(w##R##_12, x3.x, A); A=fmaf(w##R##_13, x3.y, A); \
  A=fmaf(w##R##_14, x3.z, A); A=fmaf(w##R##_15, x3.w, A); } while(0)

// dot phase: 4 broadcast ds_read_b128 + 64 FMA + one b128 partial write
#define DOT_PHASE() do { \
  const float4* _hp = (const float4*)(h_lds + 16*cg); \
  float4 x0=_hp[0], x1=_hp[1], x2=_hp[2], x3=_hp[3]; \
  float a0=0.f, a1=0.f, a2=0.f, a3=0.f; \
  FMA_ROW(0,a0); FMA_ROW(1,a1); FMA_ROW(2,a2); FMA_ROW(3,a3); \
  *(float4*)&part[cg*GG + rg*4] = make_float4(a0,a1,a2,a3); \
} while(0)

// psum + nonlinearity: thread q (<128) produces rows 4q..4q+3 (one gate type).
__device__ __forceinline__ void psum_nl(const float* part, float* nlg, int q,
                                        float u, float4 cwih4, float4 cb4) {
    float4 s4 = *(const float4*)&part[4 * q];
    #pragma unroll
    for (int c = 1; c < 8; ++c) {
        float4 p4 = *(const float4*)&part[c * GG + 4 * q];
        s4.x += p4.x; s4.y += p4.y; s4.z += p4.z; s4.w += p4.w;
    }
    const bool istanh = (q >= 64) && (q < 96);
    const float sc = istanh ? 2.0f : 1.0f;
    const float cc = istanh ? -1.0f : 0.0f;
    float4 n4;
    n4.x = fmaf(sc, sig_(sc * (s4.x + fmaf(u, cwih4.x, cb4.x))), cc);
    n4.y = fmaf(sc, sig_(sc * (s4.y + fmaf(u, cwih4.y, cb4.y))), cc);
    n4.z = fmaf(sc, sig_(sc * (s4.z + fmaf(u, cwih4.z, cb4.z))), cc);
    n4.w = fmaf(sc, sig_(sc * (s4.w + fmaf(u, cwih4.w, cb4.w))), cc);
    *(float4*)&nlg[4 * q] = n4;
}

// ---------------------------------------------------------------------------
// Encoder: variant A attrs -- raw flat_work_group_size + waves_per_eu(4,4).
// ---------------------------------------------------------------------------
__global__ __attribute__((amdgpu_flat_work_group_size(1024, 1024),
                          amdgpu_waves_per_eu(4, 4)))
void enc_kernel(const float* __restrict__ x,
                const float* __restrict__ enc_wih,
                const float* __restrict__ enc_whh,
                const float* __restrict__ enc_bias,
                float* __restrict__ hc_ws)
{
    const int t  = threadIdx.x;
    const int rg = t & 127;
    const int cg = t >> 7;
    const int b  = blockIdx.x;

    __shared__ __align__(16) float h_lds[EE];
    __shared__ __align__(16) float part[8 * GG];
    __shared__ __align__(16) float nlg[GG];
    __shared__ float xbuf[2];

    DECLW;
    float c_reg = 0.0f;
    float4 cwih4 = make_float4(0.f,0.f,0.f,0.f);
    float4 cb4   = make_float4(0.f,0.f,0.f,0.f);

    LOADW(enc_whh + (4 * rg) * EE + 16 * cg);
    if (t < EE) {
        cwih4 = *(const float4*)(enc_wih + 4 * t);
        cb4   = *(const float4*)(enc_bias + 4 * t);
        h_lds[t] = 0.0f;
    }
    if (t == 512) xbuf[0] = x[b * XROW + 0];
    __syncthreads();

    for (int s = 0; s < TT; ++s) {
        KEEPW;
        DOT_PHASE();
        __syncthreads();
        if (t < EE) psum_nl(part, nlg, t, xbuf[s & 1], cwih4, cb4);
        if (t == 512 && s + 1 < TT) xbuf[(s + 1) & 1] = x[b * XROW + s + 1];
        __syncthreads();
        if (t < EE) {
            float i_ = nlg[t], f_ = nlg[EE + t], g_ = nlg[2*EE + t], o_ = nlg[3*EE + t];
            c_reg = fmaf(f_, c_reg, i_ * g_);
            h_lds[t] = o_ * tanh2_(c_reg);
        }
        __syncthreads();
    }

    if (t < EE) {
        hc_ws[b * EE + t] = h_lds[t];
        hc_ws[BB * EE + b * EE + t] = c_reg;
    }
}

// ---------------------------------------------------------------------------
// Decoder: variant B attrs -- flat_work_group_size + amdgpu_num_vgpr(128).
// ---------------------------------------------------------------------------
__global__ __attribute__((amdgpu_flat_work_group_size(1024, 1024),
                          amdgpu_num_vgpr(128)))
void dec_kernel(const float* __restrict__ x,
                const float* __restrict__ dec_wih,
                const float* __restrict__ dec_whh,
                const float* __restrict__ dec_bias,
                const float* __restrict__ lin_w,
                const float* __restrict__ lin_b,
                const float* __restrict__ hc_ws,
                float* __restrict__ out)
{
    const int t  = threadIdx.x;
    const int rg = t & 127;
    const int cg = t >> 7;
    const int b  = blockIdx.x;

    __shared__ __align__(16) float h_lds[EE];
    __shared__ __align__(16) float part[8 * GG];
    __shared__ __align__(16) float nlg[GG];
    __shared__ __align__(16) float out_lds[TT];
    __shared__ float xbuf[2];
    __shared__ float osum[2];

    const int id = (int)x[b * XROW + TT];

    DECLW;
    float c_reg = 0.0f;
    float4 cwih4 = make_float4(0.f,0.f,0.f,0.f);
    float4 cb4   = make_float4(0.f,0.f,0.f,0.f);
    const float lb_v = lin_b[id];
    float wl = 0.0f;

    LOADW(dec_whh + id * GG * EE + (4 * rg) * EE + 16 * cg);
    if (t < EE) {
        cwih4 = *(const float4*)(dec_wih + id * GG + 4 * t);
        cb4   = *(const float4*)(dec_bias + id * GG + 4 * t);
        float hv = hc_ws[b * EE + t];
        h_lds[t] = hv;
        c_reg = hc_ws[BB * EE + b * EE + t];
        wl = lin_w[id * EE + t];
        float p = hv * wl;
        #pragma unroll
        for (int off = 32; off >= 1; off >>= 1) p += __shfl_xor(p, off);
        if ((t & 63) == 0) osum[t >> 6] = p;
    }
    __syncthreads();
    if (t == 512) xbuf[0] = osum[0] + osum[1] + lb_v;   // u0
    __syncthreads();

    for (int s = 0; s < TT; ++s) {
        KEEPW;
        DOT_PHASE();
        __syncthreads();
        if (t < EE) psum_nl(part, nlg, t, xbuf[s & 1], cwih4, cb4);
        // u_{s+1} = rev[s] = x[b][255-s]
        if (t == 512 && s + 1 < TT) xbuf[(s + 1) & 1] = x[b * XROW + (TT - 1 - s)];
        // previous step's output (osum from step s-1, stable this phase)
        if (t == 513 && s > 0) out_lds[TT - s] = osum[0] + osum[1] + lb_v;
        __syncthreads();
        if (t < EE) {
            float i_ = nlg[t], f_ = nlg[EE + t], g_ = nlg[2*EE + t], o_ = nlg[3*EE + t];
            c_reg = fmaf(f_, c_reg, i_ * g_);
            float h_new = o_ * tanh2_(c_reg);
            h_lds[t] = h_new;
            float p = h_new * wl;
            #pragma unroll
            for (int off = 32; off >= 1; off >>= 1) p += __shfl_xor(p, off);
            if ((t & 63) == 0) osum[t >> 6] = p;
        }
        __syncthreads();
    }
    if (t == 512) out_lds[0] = osum[0] + osum[1] + lb_v;  // step 255 -> pos 0
    __syncthreads();

    if (t < 64) *(float4*)(out + b * TT + 4 * t) = ((const float4*)out_lds)[t];
}

extern "C" void kernel_launch(void* const* d_in, const int* in_sizes, int n_in,
                              void* d_out, int out_size, void* d_ws, size_t ws_size,
                              hipStream_t stream) {
    const float* x       = (const float*)d_in[0];
    const float* enc_wih = (const float*)d_in[1];
    const float* enc_whh = (const float*)d_in[2];
    const float* enc_b   = (const float*)d_in[3];
    const float* dec_wih = (const float*)d_in[4];
    const float* dec_whh = (const float*)d_in[5];
    const float* dec_b   = (const float*)d_in[6];
    const float* lin_w   = (const float*)d_in[7];
    const float* lin_b   = (const float*)d_in[8];
    float* out = (float*)d_out;
    float* ws  = (float*)d_ws;  // 2*B*E floats = 512 KB

    hipLaunchKernelGGL(enc_kernel, dim3(BB), dim3(1024), 0, stream,
                       x, enc_wih, enc_whh, enc_b, ws);
    hipLaunchKernelGGL(dec_kernel, dim3(BB), dim3(1024), 0, stream,
                       x, dec_wih, dec_whh, dec_b, lin_w, lin_b, ws, out);
}